// Round 17
// baseline (38.649 us; speedup 1.0000x reference)
//
#include <hip/hip_runtime.h>
#include <math.h>

// B=4, C=64, H=W=128, OUTC=64, KS=3, taps N=9, K = 9*64 = 576. All fp16 data, f32 accum.
// ws layout (bytes):
//   x_t   fp16 [4][128][128][64]   @ 0        (8 MB) NHWC
//   cwtf  fp16 [9][2][4][64][8]    @ 8388608  (72 KB) main-conv B-fragments
//   pwtf  fp16 [9][2][2][64][8]    @ 8462336  (36 KB) offset-conv B-fragments (rows>=18 zero)
#define CWTF_OFF 8388608
#define PWTF_OFF (CWTF_OFF + 73728)

typedef __attribute__((ext_vector_type(8))) _Float16 half8;
typedef __attribute__((ext_vector_type(8))) unsigned short ushort8;
typedef __attribute__((ext_vector_type(4))) float f32x4;
typedef __attribute__((ext_vector_type(4))) unsigned int u32x4;

__device__ inline unsigned short f2h(float f) {
    _Float16 h = (_Float16)f; return __builtin_bit_cast(unsigned short, h);
}

// ---------------- prep: x NCHW f32 -> NHWC fp16, + weights -> fragment order (r11 version) ----------------
__global__ __launch_bounds__(256) void k_prep(const float* __restrict__ x,
                                              unsigned int* __restrict__ x_t_u32,
                                              const float* __restrict__ conv_w,
                                              const float* __restrict__ p_w,
                                              unsigned short* __restrict__ cwtf,
                                              unsigned short* __restrict__ pwtf) {
    if (blockIdx.x < 512) {
        __shared__ float t[64][129];
        int b = blockIdx.x >> 7;
        int i = blockIdx.x & 127;
        for (int idx = threadIdx.x; idx < 64 * 128; idx += 256) {
            int c = idx >> 7, j = idx & 127;
            t[c][j] = x[(((size_t)(b * 64 + c) * 128 + i) << 7) + j];
        }
        __syncthreads();
        unsigned int* dst = x_t_u32 + ((size_t)(b * 128 + i)) * 128 * 32;
        for (int idx2 = threadIdx.x; idx2 < 4096; idx2 += 256) {
            int j = idx2 >> 5, c2 = idx2 & 31;
            unsigned int lo = f2h(t[2 * c2][j]);
            unsigned int hi = f2h(t[2 * c2 + 1][j]);
            dst[idx2] = lo | (hi << 16);
        }
    } else {
        int tid = (blockIdx.x - 512) * 256 + threadIdx.x;
        if (tid < 36864) {
            int e = tid & 7, lane = (tid >> 3) & 63, nb = (tid >> 9) & 3, h = (tid >> 11) & 1, n = tid >> 12;
            int o = nb * 16 + (lane & 15);
            int c = h * 32 + ((lane >> 4) << 3) + e;
            cwtf[tid] = f2h(conv_w[(o * 64 + c) * 9 + n]);
        } else if (tid < 36864 + 18432) {
            int t2 = tid - 36864;
            int e = t2 & 7, lane = (t2 >> 3) & 63, nb = (t2 >> 9) & 1, h = (t2 >> 10) & 1, n = t2 >> 11;
            int np = nb * 16 + (lane & 15);
            int c = h * 32 + ((lane >> 4) << 3) + e;
            pwtf[t2] = (np < 18) ? f2h(p_w[(np * 64 + c) * 9 + n]) : (unsigned short)0;
        }
    }
}

// ---------------- fused kernel (r16 + phase-3 geom prefetch into registers, full unroll) ----------------
// Block = 64 pixels (b, i, j0..j0+63), 8 waves (512 thr): wave wv = (pg = wv&3, h = wv>>2).
// Tile margin 3: covers |offset| < 2 (8 sigma) -> slow path statistically never taken.
// geom entry: hi16 = (rec*128 + ((rec&7)<<4)) >> 4 (pre-swizzled base), low16 = f16 weight.
// Phase-3 decode: addr = (hi<<4) ^ csx  (swizzle XOR commutes: bits 4-6 only).
// MFMA 16x16x32 f16: A m=lane&15, k=8*(lane>>4)+e; B n=lane&15 same k; D n=lane&15, m=4*(lane>>4)+reg.
#define TROWS 7
#define TCOLS 71
#define TRECS (TROWS * TCOLS)      // 497 records of 128 B (64 ch fp16)
#define TILE_B (TRECS * 128)       // 63616 B
#define OFF_OFFS TILE_B            // 4608 B  [64][18] f32 (stays live through phase 3 for fallback)
#define OFF_GEOM (TILE_B + 4608)   // 9216 B  [9][64][4] packed u32
#define OFF_FLAG (TILE_B + 4608 + 9216)
// Epilogue: ep0 @ 0, ep1 @ 16640 ([64][65] f32 each) overlay the dead tile.

__global__ __launch_bounds__(512, 2) void k_fused(const unsigned short* __restrict__ x_t,
                                                  const unsigned short* __restrict__ cwtf,
                                                  const unsigned short* __restrict__ pwtf,
                                                  const float* __restrict__ p_b,
                                                  const float* __restrict__ conv_b,
                                                  float* __restrict__ out) {
    __shared__ __align__(16) unsigned char S[TILE_B + 4608 + 9216 + 16];
    unsigned char* tile = S;
    float* offs = (float*)(S + OFF_OFFS);
    unsigned char* geomB = S + OFF_GEOM;
    int* flagp = (int*)(S + OFF_FLAG);

    int bid0 = blockIdx.x;
    int bid = (bid0 & 7) * 128 + (bid0 >> 3);  // chunked XCD swizzle (1024 % 8 == 0)
    int b = bid >> 8;
    int i = (bid >> 1) & 127;
    int j0 = (bid & 1) << 6;
    int ib = i - 3, jb = j0 - 3;

    int tid = threadIdx.x;
    int lane = tid & 63;
    int r15 = lane & 15;
    int g = lane >> 4;
    int wv = tid >> 6;
    int pg = wv & 3;
    int h = wv >> 2;
    int pl = pg * 16 + r15;      // this lane's A-row pixel
    int cs = g + (h << 2);       // chunk slot: channels cs*8..cs*8+7
    int csx = cs << 4;

    if (tid == 0) *flagp = 0;

    // ---- stage swizzled x-tile (coalesced global, swizzled ds_write) ----
    for (int u = tid; u < TRECS * 8; u += 512) {
        int rec = u >> 3, chunk = u & 7;
        int trow = rec / TCOLS;
        int tcol = rec - trow * TCOLS;
        int gr = ib + trow, gc = jb + tcol;
        bool v = ((unsigned)gr < 128u) && ((unsigned)gc < 128u);
        int grc = v ? gr : 0, gcc = v ? gc : 0;
        ushort8 val = *(const ushort8*)(x_t + (((size_t)((b * 128 + grc) * 128 + gcc)) << 6) + (chunk << 3));
        if (!v) val = (ushort8)(unsigned short)0;
        *(ushort8*)(tile + rec * 128 + ((chunk ^ (rec & 7)) << 4)) = val;
    }
    __syncthreads();

    // ---- phase 1: offset conv — wave supplies its channel-half's k-block ----
    f32x4 aco0 = (f32x4)0.f, aco1 = (f32x4)0.f;
    for (int n = 0; n < 9; ++n) {
        int du = n / 3 - 1, dv = n % 3 - 1;
        int trec = (du + 3) * TCOLS + (pl + dv + 3);
        int xb = trec & 7;
        half8 a = *(const half8*)(tile + trec * 128 + ((cs ^ xb) << 4));
        const unsigned short* pb = pwtf + (((n * 2 + h) * 2) << 9) + (lane << 3);
        half8 b0 = *(const half8*)pb;
        half8 b1 = *(const half8*)(pb + 512);
        aco0 = __builtin_amdgcn_mfma_f32_16x16x32_f16(a, b0, aco0, 0, 0, 0);
        aco1 = __builtin_amdgcn_mfma_f32_16x16x32_f16(a, b1, aco1, 0, 0, 0);
    }
    // cross-h reduction of offsets: h=0 writes (+bias), h=1 adds
#pragma unroll
    for (int hh = 0; hh < 2; ++hh) {
        if (h == hh) {
#pragma unroll
            for (int nb = 0; nb < 2; ++nb) {
                int np = nb * 16 + r15;
                if (np < 18) {
                    f32x4 a = nb ? aco1 : aco0;
#pragma unroll
                    for (int rr = 0; rr < 4; ++rr) {
                        int pix = pg * 16 + g * 4 + rr;
                        if (hh == 0)
                            offs[pix * 18 + np] = a[rr] + p_b[np];
                        else
                            offs[pix * 18 + np] += a[rr];
                    }
                }
            }
        }
        __syncthreads();
    }

    // ---- phase 2: bilinear geometry -> baked pre-swizzled LDS offsets ----
    for (int t = tid; t < 576; t += 512) {
        int p = t / 9;
        int n = t - p * 9;
        float ox = offs[p * 18 + n];
        float oy = offs[p * 18 + 9 + n];
        float px = ox + (float)(i + 1) + (float)(n / 3 - 1);
        float py = oy + (float)(j0 + p + 1) + (float)(n % 3 - 1);
        float fx = floorf(px), fy = floorf(py);
        float qlx = fminf(fmaxf(fx, 0.f), 129.f);
        float qrx = fminf(fmaxf(fx + 1.f, 0.f), 129.f);
        float qly = fminf(fmaxf(fy, 0.f), 129.f);
        float qry = fminf(fmaxf(fy + 1.f, 0.f), 129.f);
        float pxc = fminf(fmaxf(px, 0.f), 129.f);
        float pyc = fminf(fmaxf(py, 0.f), 129.f);
        float ax = 1.f + qlx - pxc;
        float bx = 1.f - qrx + pxc;
        float ay = 1.f + qly - pyc;
        float by = 1.f - qry + pyc;
        int rlx = (int)qlx - 1, rrx = (int)qrx - 1;
        int rly = (int)qly - 1, rry = (int)qry - 1;
        bool bad = false;
        unsigned int pk[4];
        int cx[4] = {rlx, rrx, rlx, rrx};
        int cy[4] = {rly, rry, rry, rly};
        float cw[4] = {ax * ay, bx * by, ax * by, bx * ay};
#pragma unroll
        for (int k = 0; k < 4; ++k) {
            bool v = ((unsigned)cx[k] < 128u) && ((unsigned)cy[k] < 128u);
            bool intile = (((unsigned)(cx[k] - ib) < (unsigned)TROWS) &&
                           ((unsigned)(cy[k] - jb) < (unsigned)TCOLS));
            unsigned rec = (unsigned)(cx[k] - ib) * TCOLS + (unsigned)(cy[k] - jb);
            pk[k] = (v && intile) ? (((rec * 8u + (rec & 7u)) << 16) | f2h(cw[k])) : 0u;
            bad = bad || (v && !intile);
        }
        *(u32x4*)(geomB + ((n * 64 + p) << 4)) = (u32x4){pk[0], pk[1], pk[2], pk[3]};
        if (bad) *flagp = 1;
    }
    __syncthreads();

    // ---- phase 3: main conv — geom prefetched to registers, fully unrolled taps ----
    f32x4 acc[4];
#pragma unroll
    for (int nb = 0; nb < 4; ++nb) acc[nb] = (f32x4)0.f;
    bool fast = (*flagp == 0);

    if (fast) {
        u32x4 gq[9];
#pragma unroll
        for (int n = 0; n < 9; ++n)
            gq[n] = *(const u32x4*)(geomB + ((n * 64 + pl) << 4));
#pragma unroll
        for (int n = 0; n < 9; ++n) {
            half8 Bf[4];
#pragma unroll
            for (int nb = 0; nb < 4; ++nb)
                Bf[nb] = *(const half8*)(cwtf + ((((n * 2 + h) << 2) + nb) << 9) + (lane << 3));
            half8 av = (half8)(_Float16)0;
#pragma unroll
            for (int k = 0; k < 4; ++k) {
                unsigned int p = gq[n][k];
                _Float16 wk = __builtin_bit_cast(_Float16, (unsigned short)(p & 0xFFFFu));
                half8 u = *(const half8*)(tile + (((p >> 16) << 4) ^ (unsigned)csx));
                av += u * wk;   // v_pk_fma_f16
            }
#pragma unroll
            for (int nb = 0; nb < 4; ++nb)
                acc[nb] = __builtin_amdgcn_mfma_f32_16x16x32_f16(av, Bf[nb], acc[nb], 0, 0, 0);
        }
    } else {
        // rare path: recompute geometry from offs (still live) per lane, gather from global
        for (int n = 0; n < 9; ++n) {
            half8 Bf[4];
#pragma unroll
            for (int nb = 0; nb < 4; ++nb)
                Bf[nb] = *(const half8*)(cwtf + ((((n * 2 + h) << 2) + nb) << 9) + (lane << 3));
            float ox = offs[pl * 18 + n];
            float oy = offs[pl * 18 + 9 + n];
            float px = ox + (float)(i + 1) + (float)(n / 3 - 1);
            float py = oy + (float)(j0 + pl + 1) + (float)(n % 3 - 1);
            float fx = floorf(px), fy = floorf(py);
            float qlx = fminf(fmaxf(fx, 0.f), 129.f);
            float qrx = fminf(fmaxf(fx + 1.f, 0.f), 129.f);
            float qly = fminf(fmaxf(fy, 0.f), 129.f);
            float qry = fminf(fmaxf(fy + 1.f, 0.f), 129.f);
            float pxc = fminf(fmaxf(px, 0.f), 129.f);
            float pyc = fminf(fmaxf(py, 0.f), 129.f);
            float ax = 1.f + qlx - pxc;
            float bx = 1.f - qrx + pxc;
            float ay = 1.f + qly - pyc;
            float by = 1.f - qry + pyc;
            int cx[4] = {(int)qlx - 1, (int)qrx - 1, (int)qlx - 1, (int)qrx - 1};
            int cy[4] = {(int)qly - 1, (int)qry - 1, (int)qry - 1, (int)qly - 1};
            float cw[4] = {ax * ay, bx * by, ax * by, bx * ay};
            half8 av = (half8)(_Float16)0;
#pragma unroll
            for (int k = 0; k < 4; ++k) {
                bool v = ((unsigned)cx[k] < 128u) && ((unsigned)cy[k] < 128u);
                size_t base = v ? (((size_t)((b * 128 + cx[k]) * 128 + cy[k])) << 6) : 0;
                _Float16 wk = v ? (_Float16)cw[k] : (_Float16)0.f;
                half8 u = *(const half8*)(x_t + base + (cs << 3));
                av += u * wk;
            }
#pragma unroll
            for (int nb = 0; nb < 4; ++nb)
                acc[nb] = __builtin_amdgcn_mfma_f32_16x16x32_f16(av, Bf[nb], acc[nb], 0, 0, 0);
        }
    }
    __syncthreads();  // tile dead; reuse as ep0/ep1

    // ---- epilogue: disjoint per-half regions, ONE barrier, summed at store ----
    {
        float* epH = (float*)(S + (h ? 16640 : 0));
#pragma unroll
        for (int nb = 0; nb < 4; ++nb) {
            int o = nb * 16 + r15;
#pragma unroll
            for (int rr = 0; rr < 4; ++rr) {
                int pix = pg * 16 + g * 4 + rr;
                epH[o * 65 + pix] = acc[nb][rr];
            }
        }
    }
    __syncthreads();
    {
        float* e0 = (float*)S;
        float* e1 = (float*)(S + 16640);
        for (int t = tid; t < 4096; t += 512) {
            int o = t >> 6;
            int p = t & 63;
            out[(((size_t)(b * 64 + o)) << 14) + (i << 7) + j0 + p] =
                e0[o * 65 + p] + e1[o * 65 + p] + conv_b[o];
        }
    }
}

extern "C" void kernel_launch(void* const* d_in, const int* in_sizes, int n_in,
                              void* d_out, int out_size, void* d_ws, size_t ws_size,
                              hipStream_t stream) {
    const float* x = (const float*)d_in[0];
    const float* p_w = (const float*)d_in[1];
    const float* p_b = (const float*)d_in[2];
    const float* conv_w = (const float*)d_in[3];
    const float* conv_b = (const float*)d_in[4];
    float* out = (float*)d_out;
    char* ws = (char*)d_ws;

    unsigned short* x_t = (unsigned short*)(ws);
    unsigned short* cwtf = (unsigned short*)(ws + CWTF_OFF);
    unsigned short* pwtf = (unsigned short*)(ws + PWTF_OFF);

    k_prep<<<728, 256, 0, stream>>>(x, (unsigned int*)x_t, conv_w, p_w, cwtf, pwtf);
    k_fused<<<1024, 512, 0, stream>>>(x_t, cwtf, pwtf, p_b, conv_b, out);
}

// Round 18
// 38.260 us; speedup vs baseline: 1.0102x; 1.0102x over previous
//
#include <hip/hip_runtime.h>
#include <math.h>

// B=4, C=64, H=W=128, OUTC=64, KS=3, taps N=9, K = 9*64 = 576. All fp16 data, f32 accum.
// ws layout (bytes):
//   x_t   fp16 [4][128][128][64]   @ 0        (8 MB) NHWC
//   cwtf  fp16 [9][4][2][64][8]    @ 8388608  (72 KB) main-conv B-frags for 32x32x16:
//         cwtf[((n*4+kq)*2+oh)*512 + lane*8 + e] = conv_w[o=oh*32+(lane&31)][c=kq*16+(lane>>5)*8+e][n]
//   pwtf  fp16 [9][2][2][64][8]    @ 8462336  (36 KB) offset-conv B-fragments (rows>=18 zero)
#define CWTF_OFF 8388608
#define PWTF_OFF (CWTF_OFF + 73728)

typedef __attribute__((ext_vector_type(8))) _Float16 half8;
typedef __attribute__((ext_vector_type(8))) unsigned short ushort8;
typedef __attribute__((ext_vector_type(4))) float f32x4;
typedef __attribute__((ext_vector_type(16))) float f32x16;
typedef __attribute__((ext_vector_type(4))) unsigned int u32x4;

__device__ inline unsigned short f2h(float f) {
    _Float16 h = (_Float16)f; return __builtin_bit_cast(unsigned short, h);
}

// ---------------- prep: x NCHW f32 -> NHWC fp16, + weights -> fragment order ----------------
__global__ __launch_bounds__(256) void k_prep(const float* __restrict__ x,
                                              unsigned int* __restrict__ x_t_u32,
                                              const float* __restrict__ conv_w,
                                              const float* __restrict__ p_w,
                                              unsigned short* __restrict__ cwtf,
                                              unsigned short* __restrict__ pwtf) {
    if (blockIdx.x < 512) {
        __shared__ float t[64][129];
        int b = blockIdx.x >> 7;
        int i = blockIdx.x & 127;
        for (int idx = threadIdx.x; idx < 64 * 128; idx += 256) {
            int c = idx >> 7, j = idx & 127;
            t[c][j] = x[(((size_t)(b * 64 + c) * 128 + i) << 7) + j];
        }
        __syncthreads();
        unsigned int* dst = x_t_u32 + ((size_t)(b * 128 + i)) * 128 * 32;
        for (int idx2 = threadIdx.x; idx2 < 4096; idx2 += 256) {
            int j = idx2 >> 5, c2 = idx2 & 31;
            unsigned int lo = f2h(t[2 * c2][j]);
            unsigned int hi = f2h(t[2 * c2 + 1][j]);
            dst[idx2] = lo | (hi << 16);
        }
    } else {
        int tid = (blockIdx.x - 512) * 256 + threadIdx.x;
        if (tid < 36864) {
            // 32x32x16 B-frag order: e b0-2, lane b3-8, oh b9, kq b10-11, n b12+
            int e = tid & 7, lane = (tid >> 3) & 63, oh = (tid >> 9) & 1, kq = (tid >> 10) & 3, n = tid >> 12;
            int o = oh * 32 + (lane & 31);
            int c = kq * 16 + ((lane >> 5) << 3) + e;
            cwtf[tid] = f2h(conv_w[(o * 64 + c) * 9 + n]);
        } else if (tid < 36864 + 18432) {
            int t2 = tid - 36864;
            int e = t2 & 7, lane = (t2 >> 3) & 63, nb = (t2 >> 9) & 1, h = (t2 >> 10) & 1, n = t2 >> 11;
            int np = nb * 16 + (lane & 15);
            int c = h * 32 + ((lane >> 4) << 3) + e;
            pwtf[t2] = (np < 18) ? f2h(p_w[(np * 64 + c) * 9 + n]) : (unsigned short)0;
        }
    }
}

// ---------------- fused kernel (r16 + phase-3 switched to 32x32x16 MFMA, kq-quartered) ----------------
// Block = 64 pixels (b, i, j0..j0+63), 8 waves (512 thr).
// Phase 1/2: wave wv = (pg = wv&3, h = wv>>2), 16x16x32 (unchanged from r16).
// Phase 3: wave wv = (pg2 = wv&1 [32 px], kq = wv>>1 [K-quarter]); per tap ONE bilinear
//   A-frag feeds TWO 32x32x16 MFMAs (oh = outc halves) -> B traffic halved, MFMA issues 72->18.
// 32x32x16 f16 layout: A m=lane&31, k=8*(lane>>5)+e; B n=lane&31, same k;
//                      D col=lane&31, row=(reg&3)+8*(reg>>2)+4*(lane>>5).
#define TROWS 7
#define TCOLS 71
#define TRECS (TROWS * TCOLS)      // 497 records of 128 B (64 ch fp16)
#define TILE_B (TRECS * 128)       // 63616 B
#define OFF_OFFS TILE_B            // 4608 B  [64][18] f32 (live through phase 3 for fallback)
#define OFF_GEOM (TILE_B + 4608)   // 9216 B  [9][64][4] packed u32
#define OFF_FLAG (TILE_B + 4608 + 9216)
// Epilogue: ep0 @ 0 (kq 0+1), ep1 @ 16640 (kq 2+3), [64][65] f32 each, overlay dead tile.

__global__ __launch_bounds__(512, 2) void k_fused(const unsigned short* __restrict__ x_t,
                                                  const unsigned short* __restrict__ cwtf,
                                                  const unsigned short* __restrict__ pwtf,
                                                  const float* __restrict__ p_b,
                                                  const float* __restrict__ conv_b,
                                                  float* __restrict__ out) {
    __shared__ __align__(16) unsigned char S[TILE_B + 4608 + 9216 + 16];
    unsigned char* tile = S;
    float* offs = (float*)(S + OFF_OFFS);
    unsigned char* geomB = S + OFF_GEOM;
    int* flagp = (int*)(S + OFF_FLAG);

    int bid0 = blockIdx.x;
    int bid = (bid0 & 7) * 128 + (bid0 >> 3);  // chunked XCD swizzle (1024 % 8 == 0)
    int b = bid >> 8;
    int i = (bid >> 1) & 127;
    int j0 = (bid & 1) << 6;
    int ib = i - 3, jb = j0 - 3;

    int tid = threadIdx.x;
    int lane = tid & 63;
    int r15 = lane & 15;
    int g = lane >> 4;
    int wv = tid >> 6;
    int pg = wv & 3;             // phase-1 pixel group
    int h = wv >> 2;             // phase-1 k-half
    int pl = pg * 16 + r15;
    int cs = g + (h << 2);

    if (tid == 0) *flagp = 0;

    // ---- stage swizzled x-tile (coalesced global, swizzled ds_write) ----
    for (int u = tid; u < TRECS * 8; u += 512) {
        int rec = u >> 3, chunk = u & 7;
        int trow = rec / TCOLS;
        int tcol = rec - trow * TCOLS;
        int gr = ib + trow, gc = jb + tcol;
        bool v = ((unsigned)gr < 128u) && ((unsigned)gc < 128u);
        int grc = v ? gr : 0, gcc = v ? gc : 0;
        ushort8 val = *(const ushort8*)(x_t + (((size_t)((b * 128 + grc) * 128 + gcc)) << 6) + (chunk << 3));
        if (!v) val = (ushort8)(unsigned short)0;
        *(ushort8*)(tile + rec * 128 + ((chunk ^ (rec & 7)) << 4)) = val;
    }
    __syncthreads();

    // ---- phase 1: offset conv — 16x16x32, wave supplies its channel-half's k-block ----
    f32x4 aco0 = (f32x4)0.f, aco1 = (f32x4)0.f;
    for (int n = 0; n < 9; ++n) {
        int du = n / 3 - 1, dv = n % 3 - 1;
        int trec = (du + 3) * TCOLS + (pl + dv + 3);
        int xb = trec & 7;
        half8 a = *(const half8*)(tile + trec * 128 + ((cs ^ xb) << 4));
        const unsigned short* pb = pwtf + (((n * 2 + h) * 2) << 9) + (lane << 3);
        half8 b0 = *(const half8*)pb;
        half8 b1 = *(const half8*)(pb + 512);
        aco0 = __builtin_amdgcn_mfma_f32_16x16x32_f16(a, b0, aco0, 0, 0, 0);
        aco1 = __builtin_amdgcn_mfma_f32_16x16x32_f16(a, b1, aco1, 0, 0, 0);
    }
#pragma unroll
    for (int hh = 0; hh < 2; ++hh) {
        if (h == hh) {
#pragma unroll
            for (int nb = 0; nb < 2; ++nb) {
                int np = nb * 16 + r15;
                if (np < 18) {
                    f32x4 a = nb ? aco1 : aco0;
#pragma unroll
                    for (int rr = 0; rr < 4; ++rr) {
                        int pix = pg * 16 + g * 4 + rr;
                        if (hh == 0)
                            offs[pix * 18 + np] = a[rr] + p_b[np];
                        else
                            offs[pix * 18 + np] += a[rr];
                    }
                }
            }
        }
        __syncthreads();
    }

    // ---- phase 2: bilinear geometry -> baked pre-swizzled LDS offsets ----
    for (int t = tid; t < 576; t += 512) {
        int p = t / 9;
        int n = t - p * 9;
        float ox = offs[p * 18 + n];
        float oy = offs[p * 18 + 9 + n];
        float px = ox + (float)(i + 1) + (float)(n / 3 - 1);
        float py = oy + (float)(j0 + p + 1) + (float)(n % 3 - 1);
        float fx = floorf(px), fy = floorf(py);
        float qlx = fminf(fmaxf(fx, 0.f), 129.f);
        float qrx = fminf(fmaxf(fx + 1.f, 0.f), 129.f);
        float qly = fminf(fmaxf(fy, 0.f), 129.f);
        float qry = fminf(fmaxf(fy + 1.f, 0.f), 129.f);
        float pxc = fminf(fmaxf(px, 0.f), 129.f);
        float pyc = fminf(fmaxf(py, 0.f), 129.f);
        float ax = 1.f + qlx - pxc;
        float bx = 1.f - qrx + pxc;
        float ay = 1.f + qly - pyc;
        float by = 1.f - qry + pyc;
        int rlx = (int)qlx - 1, rrx = (int)qrx - 1;
        int rly = (int)qly - 1, rry = (int)qry - 1;
        bool bad = false;
        unsigned int pk[4];
        int cx[4] = {rlx, rrx, rlx, rrx};
        int cy[4] = {rly, rry, rry, rly};
        float cw[4] = {ax * ay, bx * by, ax * by, bx * ay};
#pragma unroll
        for (int k = 0; k < 4; ++k) {
            bool v = ((unsigned)cx[k] < 128u) && ((unsigned)cy[k] < 128u);
            bool intile = (((unsigned)(cx[k] - ib) < (unsigned)TROWS) &&
                           ((unsigned)(cy[k] - jb) < (unsigned)TCOLS));
            unsigned rec = (unsigned)(cx[k] - ib) * TCOLS + (unsigned)(cy[k] - jb);
            pk[k] = (v && intile) ? (((rec * 8u + (rec & 7u)) << 16) | f2h(cw[k])) : 0u;
            bad = bad || (v && !intile);
        }
        *(u32x4*)(geomB + ((n * 64 + p) << 4)) = (u32x4){pk[0], pk[1], pk[2], pk[3]};
        if (bad) *flagp = 1;
    }
    __syncthreads();

    // ---- phase 3: main conv — 32x32x16, wave = (pg2, kq); one A-frag feeds 2 MFMAs ----
    int pg2 = wv & 1;
    int kq = wv >> 1;
    int pl3 = pg2 * 32 + (lane & 31);                    // A-row pixel
    unsigned csx3 = (unsigned)((kq * 2 + (lane >> 5)) << 4);  // channel chunk byte offset
    f32x16 acc0 = (f32x16)0.f, acc1 = (f32x16)0.f;
    bool fast = (*flagp == 0);

    if (fast) {
        for (int n = 0; n < 9; ++n) {
            u32x4 gq = *(const u32x4*)(geomB + ((n * 64 + pl3) << 4));
            const unsigned short* cb = cwtf + (((n * 4 + kq) * 2) << 9) + (lane << 3);
            half8 Bf0 = *(const half8*)cb;
            half8 Bf1 = *(const half8*)(cb + 512);
            half8 av = (half8)(_Float16)0;
#pragma unroll
            for (int k = 0; k < 4; ++k) {
                unsigned int p = gq[k];
                _Float16 wk = __builtin_bit_cast(_Float16, (unsigned short)(p & 0xFFFFu));
                half8 u = *(const half8*)(tile + (((p >> 16) << 4) ^ csx3));
                av += u * wk;   // v_pk_fma_f16
            }
            acc0 = __builtin_amdgcn_mfma_f32_32x32x16_f16(av, Bf0, acc0, 0, 0, 0);
            acc1 = __builtin_amdgcn_mfma_f32_32x32x16_f16(av, Bf1, acc1, 0, 0, 0);
        }
    } else {
        // rare path: recompute geometry from offs (still live), gather from global
        int cs3e = (kq * 2 + (lane >> 5)) << 3;   // channel element offset
        for (int n = 0; n < 9; ++n) {
            const unsigned short* cb = cwtf + (((n * 4 + kq) * 2) << 9) + (lane << 3);
            half8 Bf0 = *(const half8*)cb;
            half8 Bf1 = *(const half8*)(cb + 512);
            float ox = offs[pl3 * 18 + n];
            float oy = offs[pl3 * 18 + 9 + n];
            float px = ox + (float)(i + 1) + (float)(n / 3 - 1);
            float py = oy + (float)(j0 + pl3 + 1) + (float)(n % 3 - 1);
            float fx = floorf(px), fy = floorf(py);
            float qlx = fminf(fmaxf(fx, 0.f), 129.f);
            float qrx = fminf(fmaxf(fx + 1.f, 0.f), 129.f);
            float qly = fminf(fmaxf(fy, 0.f), 129.f);
            float qry = fminf(fmaxf(fy + 1.f, 0.f), 129.f);
            float pxc = fminf(fmaxf(px, 0.f), 129.f);
            float pyc = fminf(fmaxf(py, 0.f), 129.f);
            float ax = 1.f + qlx - pxc;
            float bx = 1.f - qrx + pxc;
            float ay = 1.f + qly - pyc;
            float by = 1.f - qry + pyc;
            int cx[4] = {(int)qlx - 1, (int)qrx - 1, (int)qlx - 1, (int)qrx - 1};
            int cy[4] = {(int)qly - 1, (int)qry - 1, (int)qry - 1, (int)qly - 1};
            float cw[4] = {ax * ay, bx * by, ax * by, bx * ay};
            half8 av = (half8)(_Float16)0;
#pragma unroll
            for (int k = 0; k < 4; ++k) {
                bool v = ((unsigned)cx[k] < 128u) && ((unsigned)cy[k] < 128u);
                size_t base = v ? (((size_t)((b * 128 + cx[k]) * 128 + cy[k])) << 6) : 0;
                _Float16 wk = v ? (_Float16)cw[k] : (_Float16)0.f;
                half8 u = *(const half8*)(x_t + base + cs3e);
                av += u * wk;
            }
            acc0 = __builtin_amdgcn_mfma_f32_32x32x16_f16(av, Bf0, acc0, 0, 0, 0);
            acc1 = __builtin_amdgcn_mfma_f32_32x32x16_f16(av, Bf1, acc1, 0, 0, 0);
        }
    }
    __syncthreads();  // tile dead; reuse as ep0/ep1

    // ---- epilogue: kq-pair reduce into ep0 (kq 0+1) / ep1 (kq 2+3), then summed store ----
    {
        float* epH = (float*)(S + ((kq >> 1) ? 16640 : 0));
#pragma unroll
        for (int round = 0; round < 2; ++round) {
            if ((kq & 1) == round) {
#pragma unroll
                for (int oh = 0; oh < 2; ++oh) {
                    int o = oh * 32 + (lane & 31);
                    f32x16 a = oh ? acc1 : acc0;
#pragma unroll
                    for (int reg = 0; reg < 16; ++reg) {
                        int pix = pg2 * 32 + ((reg & 3) + 8 * (reg >> 2) + 4 * (lane >> 5));
                        if (round == 0)
                            epH[o * 65 + pix] = a[reg];
                        else
                            epH[o * 65 + pix] += a[reg];
                    }
                }
            }
            __syncthreads();
        }
    }
    {
        float* e0 = (float*)S;
        float* e1 = (float*)(S + 16640);
        for (int t = tid; t < 4096; t += 512) {
            int o = t >> 6;
            int p = t & 63;
            out[(((size_t)(b * 64 + o)) << 14) + (i << 7) + j0 + p] =
                e0[o * 65 + p] + e1[o * 65 + p] + conv_b[o];
        }
    }
}

extern "C" void kernel_launch(void* const* d_in, const int* in_sizes, int n_in,
                              void* d_out, int out_size, void* d_ws, size_t ws_size,
                              hipStream_t stream) {
    const float* x = (const float*)d_in[0];
    const float* p_w = (const float*)d_in[1];
    const float* p_b = (const float*)d_in[2];
    const float* conv_w = (const float*)d_in[3];
    const float* conv_b = (const float*)d_in[4];
    float* out = (float*)d_out;
    char* ws = (char*)d_ws;

    unsigned short* x_t = (unsigned short*)(ws);
    unsigned short* cwtf = (unsigned short*)(ws + CWTF_OFF);
    unsigned short* pwtf = (unsigned short*)(ws + PWTF_OFF);

    k_prep<<<728, 256, 0, stream>>>(x, (unsigned int*)x_t, conv_w, p_w, cwtf, pwtf);
    k_fused<<<1024, 512, 0, stream>>>(x_t, cwtf, pwtf, p_b, conv_b, out);
}

// Round 19
// 36.964 us; speedup vs baseline: 1.0456x; 1.0351x over previous
//
#include <hip/hip_runtime.h>
#include <math.h>

// B=4, C=64, H=W=128, OUTC=64, KS=3, taps N=9, K = 9*64 = 576. All fp16 data, f32 accum.
// ws layout (bytes):
//   x_t   fp16 [4][128][128][64]   @ 0        (8 MB) NHWC
//   cwtf  fp16 [9][4][2][64][8]    @ 8388608  (72 KB) main-conv B-frags for 32x32x16:
//         cwtf[((n*4+kq)*2+oh)*512 + lane*8 + e] = conv_w[o=oh*32+(lane&31)][c=kq*16+(lane>>5)*8+e][n]
//   pwtf  fp16 [9][2][2][64][8]    @ 8462336  (36 KB) offset-conv B-fragments (rows>=18 zero)
#define CWTF_OFF 8388608
#define PWTF_OFF (CWTF_OFF + 73728)

typedef __attribute__((ext_vector_type(8))) _Float16 half8;
typedef __attribute__((ext_vector_type(8))) unsigned short ushort8;
typedef __attribute__((ext_vector_type(4))) float f32x4;
typedef __attribute__((ext_vector_type(16))) float f32x16;
typedef __attribute__((ext_vector_type(4))) unsigned int u32x4;

__device__ inline unsigned short f2h(float f) {
    _Float16 h = (_Float16)f; return __builtin_bit_cast(unsigned short, h);
}

// ---------------- prep: x NCHW f32 -> NHWC fp16, + weights -> fragment order ----------------
__global__ __launch_bounds__(256) void k_prep(const float* __restrict__ x,
                                              unsigned int* __restrict__ x_t_u32,
                                              const float* __restrict__ conv_w,
                                              const float* __restrict__ p_w,
                                              unsigned short* __restrict__ cwtf,
                                              unsigned short* __restrict__ pwtf) {
    if (blockIdx.x < 512) {
        __shared__ float t[64][129];
        int b = blockIdx.x >> 7;
        int i = blockIdx.x & 127;
        for (int idx = threadIdx.x; idx < 64 * 128; idx += 256) {
            int c = idx >> 7, j = idx & 127;
            t[c][j] = x[(((size_t)(b * 64 + c) * 128 + i) << 7) + j];
        }
        __syncthreads();
        unsigned int* dst = x_t_u32 + ((size_t)(b * 128 + i)) * 128 * 32;
        for (int idx2 = threadIdx.x; idx2 < 4096; idx2 += 256) {
            int j = idx2 >> 5, c2 = idx2 & 31;
            unsigned int lo = f2h(t[2 * c2][j]);
            unsigned int hi = f2h(t[2 * c2 + 1][j]);
            dst[idx2] = lo | (hi << 16);
        }
    } else {
        int tid = (blockIdx.x - 512) * 256 + threadIdx.x;
        if (tid < 36864) {
            // 32x32x16 B-frag order: e b0-2, lane b3-8, oh b9, kq b10-11, n b12+
            int e = tid & 7, lane = (tid >> 3) & 63, oh = (tid >> 9) & 1, kq = (tid >> 10) & 3, n = tid >> 12;
            int o = oh * 32 + (lane & 31);
            int c = kq * 16 + ((lane >> 5) << 3) + e;
            cwtf[tid] = f2h(conv_w[(o * 64 + c) * 9 + n]);
        } else if (tid < 36864 + 18432) {
            int t2 = tid - 36864;
            int e = t2 & 7, lane = (t2 >> 3) & 63, nb = (t2 >> 9) & 1, h = (t2 >> 10) & 1, n = t2 >> 11;
            int np = nb * 16 + (lane & 15);
            int c = h * 32 + ((lane >> 4) << 3) + e;
            pwtf[t2] = (np < 18) ? f2h(p_w[(np * 64 + c) * 9 + n]) : (unsigned short)0;
        }
    }
}

// ---------------- fused kernel (r18 + 2x32 pixel footprint: tile 63.6 -> 38.9 KB) ----------------
// Block = 64 pixels: rows (i, i+1) x cols (j0..j0+31). 8 waves (512 thr).
// Pixel p: row = p>>5, col = p&31. Tile rows i-3..i+4, cols j0-3..j0+34 (margin 3, 8 sigma).
// Phase 1/2: wave wv = (pg = wv&3 [16 px], h = wv>>2 [k-half]), 16x16x32.
// Phase 3: wave wv = (pg2 = wv&1 [32 px], kq = wv>>1 [K-quarter]), 32x32x16; one A-frag, 2 MFMAs.
// geom entry: hi16 = pre-swizzled LDS offset>>4, low16 = f16 weight; decode = (hi<<4)^csx.
#define TROWS 8
#define TCOLS 38
#define TRECS (TROWS * TCOLS)      // 304 records of 128 B (64 ch fp16)
#define TILE_B (TRECS * 128)       // 38912 B
#define OFF_OFFS TILE_B            // 4608 B  [64][18] f32 (live through phase 3 for fallback)
#define OFF_GEOM (TILE_B + 4608)   // 9216 B  [9][64][4] packed u32
#define OFF_FLAG (TILE_B + 4608 + 9216)
// Epilogue: ep0 @ 0 (kq 0+1), ep1 @ 16640 (kq 2+3), [64][65] f32 each, overlay dead tile (38912 B).

__global__ __launch_bounds__(512, 2) void k_fused(const unsigned short* __restrict__ x_t,
                                                  const unsigned short* __restrict__ cwtf,
                                                  const unsigned short* __restrict__ pwtf,
                                                  const float* __restrict__ p_b,
                                                  const float* __restrict__ conv_b,
                                                  float* __restrict__ out) {
    __shared__ __align__(16) unsigned char S[TILE_B + 4608 + 9216 + 16];
    unsigned char* tile = S;
    float* offs = (float*)(S + OFF_OFFS);
    unsigned char* geomB = S + OFF_GEOM;
    int* flagp = (int*)(S + OFF_FLAG);

    int bid0 = blockIdx.x;
    int bid = (bid0 & 7) * 128 + (bid0 >> 3);  // chunked XCD swizzle (1024 % 8 == 0)
    int b = bid >> 8;
    int rem = bid & 255;
    int i = (rem >> 2) * 2;      // i-pair base row
    int j0 = (rem & 3) * 32;     // j-quarter base col
    int ib = i - 3, jb = j0 - 3;

    int tid = threadIdx.x;
    int lane = tid & 63;
    int r15 = lane & 15;
    int g = lane >> 4;
    int wv = tid >> 6;
    int pg = wv & 3;             // phase-1 pixel group
    int h = wv >> 2;             // phase-1 k-half
    int pl = pg * 16 + r15;      // pixel index 0-63
    int cs = g + (h << 2);

    if (tid == 0) *flagp = 0;

    // ---- stage swizzled x-tile (coalesced global, swizzled ds_write) ----
    for (int u = tid; u < TRECS * 8; u += 512) {
        int rec = u >> 3, chunk = u & 7;
        int trow = rec / TCOLS;
        int tcol = rec - trow * TCOLS;
        int gr = ib + trow, gc = jb + tcol;
        bool v = ((unsigned)gr < 128u) && ((unsigned)gc < 128u);
        int grc = v ? gr : 0, gcc = v ? gc : 0;
        ushort8 val = *(const ushort8*)(x_t + (((size_t)((b * 128 + grc) * 128 + gcc)) << 6) + (chunk << 3));
        if (!v) val = (ushort8)(unsigned short)0;
        *(ushort8*)(tile + rec * 128 + ((chunk ^ (rec & 7)) << 4)) = val;
    }
    __syncthreads();

    // ---- phase 1: offset conv — 16x16x32, wave supplies its channel-half's k-block ----
    f32x4 aco0 = (f32x4)0.f, aco1 = (f32x4)0.f;
    {
        int ir = pl >> 5, jc = pl & 31;
        for (int n = 0; n < 9; ++n) {
            int du = n / 3 - 1, dv = n % 3 - 1;
            int trec = (ir + du + 3) * TCOLS + (jc + dv + 3);
            int xb = trec & 7;
            half8 a = *(const half8*)(tile + trec * 128 + ((cs ^ xb) << 4));
            const unsigned short* pb = pwtf + (((n * 2 + h) * 2) << 9) + (lane << 3);
            half8 b0 = *(const half8*)pb;
            half8 b1 = *(const half8*)(pb + 512);
            aco0 = __builtin_amdgcn_mfma_f32_16x16x32_f16(a, b0, aco0, 0, 0, 0);
            aco1 = __builtin_amdgcn_mfma_f32_16x16x32_f16(a, b1, aco1, 0, 0, 0);
        }
    }
#pragma unroll
    for (int hh = 0; hh < 2; ++hh) {
        if (h == hh) {
#pragma unroll
            for (int nb = 0; nb < 2; ++nb) {
                int np = nb * 16 + r15;
                if (np < 18) {
                    f32x4 a = nb ? aco1 : aco0;
#pragma unroll
                    for (int rr = 0; rr < 4; ++rr) {
                        int pix = pg * 16 + g * 4 + rr;
                        if (hh == 0)
                            offs[pix * 18 + np] = a[rr] + p_b[np];
                        else
                            offs[pix * 18 + np] += a[rr];
                    }
                }
            }
        }
        __syncthreads();
    }

    // ---- phase 2: bilinear geometry -> baked pre-swizzled LDS offsets ----
    for (int t = tid; t < 576; t += 512) {
        int p = t / 9;
        int n = t - p * 9;
        float ox = offs[p * 18 + n];
        float oy = offs[p * 18 + 9 + n];
        float px = ox + (float)(i + (p >> 5) + 1) + (float)(n / 3 - 1);
        float py = oy + (float)(j0 + (p & 31) + 1) + (float)(n % 3 - 1);
        float fx = floorf(px), fy = floorf(py);
        float qlx = fminf(fmaxf(fx, 0.f), 129.f);
        float qrx = fminf(fmaxf(fx + 1.f, 0.f), 129.f);
        float qly = fminf(fmaxf(fy, 0.f), 129.f);
        float qry = fminf(fmaxf(fy + 1.f, 0.f), 129.f);
        float pxc = fminf(fmaxf(px, 0.f), 129.f);
        float pyc = fminf(fmaxf(py, 0.f), 129.f);
        float ax = 1.f + qlx - pxc;
        float bx = 1.f - qrx + pxc;
        float ay = 1.f + qly - pyc;
        float by = 1.f - qry + pyc;
        int rlx = (int)qlx - 1, rrx = (int)qrx - 1;
        int rly = (int)qly - 1, rry = (int)qry - 1;
        bool bad = false;
        unsigned int pk[4];
        int cx[4] = {rlx, rrx, rlx, rrx};
        int cy[4] = {rly, rry, rry, rly};
        float cw[4] = {ax * ay, bx * by, ax * by, bx * ay};
#pragma unroll
        for (int k = 0; k < 4; ++k) {
            bool v = ((unsigned)cx[k] < 128u) && ((unsigned)cy[k] < 128u);
            bool intile = (((unsigned)(cx[k] - ib) < (unsigned)TROWS) &&
                           ((unsigned)(cy[k] - jb) < (unsigned)TCOLS));
            unsigned rec = (unsigned)(cx[k] - ib) * TCOLS + (unsigned)(cy[k] - jb);
            pk[k] = (v && intile) ? (((rec * 8u + (rec & 7u)) << 16) | f2h(cw[k])) : 0u;
            bad = bad || (v && !intile);
        }
        *(u32x4*)(geomB + ((n * 64 + p) << 4)) = (u32x4){pk[0], pk[1], pk[2], pk[3]};
        if (bad) *flagp = 1;
    }
    __syncthreads();

    // ---- phase 3: main conv — 32x32x16, wave = (pg2, kq); one A-frag feeds 2 MFMAs ----
    int pg2 = wv & 1;
    int kq = wv >> 1;
    int pl3 = pg2 * 32 + (lane & 31);                    // A-row pixel (0-63)
    unsigned csx3 = (unsigned)((kq * 2 + (lane >> 5)) << 4);  // channel chunk byte offset
    f32x16 acc0 = (f32x16)0.f, acc1 = (f32x16)0.f;
    bool fast = (*flagp == 0);

    if (fast) {
        for (int n = 0; n < 9; ++n) {
            u32x4 gq = *(const u32x4*)(geomB + ((n * 64 + pl3) << 4));
            const unsigned short* cb = cwtf + (((n * 4 + kq) * 2) << 9) + (lane << 3);
            half8 Bf0 = *(const half8*)cb;
            half8 Bf1 = *(const half8*)(cb + 512);
            half8 av = (half8)(_Float16)0;
#pragma unroll
            for (int k = 0; k < 4; ++k) {
                unsigned int p = gq[k];
                _Float16 wk = __builtin_bit_cast(_Float16, (unsigned short)(p & 0xFFFFu));
                half8 u = *(const half8*)(tile + (((p >> 16) << 4) ^ csx3));
                av += u * wk;   // v_pk_fma_f16
            }
            acc0 = __builtin_amdgcn_mfma_f32_32x32x16_f16(av, Bf0, acc0, 0, 0, 0);
            acc1 = __builtin_amdgcn_mfma_f32_32x32x16_f16(av, Bf1, acc1, 0, 0, 0);
        }
    } else {
        // rare path: recompute geometry from offs (still live), gather from global
        int cs3e = (kq * 2 + (lane >> 5)) << 3;   // channel element offset
        for (int n = 0; n < 9; ++n) {
            const unsigned short* cb = cwtf + (((n * 4 + kq) * 2) << 9) + (lane << 3);
            half8 Bf0 = *(const half8*)cb;
            half8 Bf1 = *(const half8*)(cb + 512);
            float ox = offs[pl3 * 18 + n];
            float oy = offs[pl3 * 18 + 9 + n];
            float px = ox + (float)(i + (pl3 >> 5) + 1) + (float)(n / 3 - 1);
            float py = oy + (float)(j0 + (pl3 & 31) + 1) + (float)(n % 3 - 1);
            float fx = floorf(px), fy = floorf(py);
            float qlx = fminf(fmaxf(fx, 0.f), 129.f);
            float qrx = fminf(fmaxf(fx + 1.f, 0.f), 129.f);
            float qly = fminf(fmaxf(fy, 0.f), 129.f);
            float qry = fminf(fmaxf(fy + 1.f, 0.f), 129.f);
            float pxc = fminf(fmaxf(px, 0.f), 129.f);
            float pyc = fminf(fmaxf(py, 0.f), 129.f);
            float ax = 1.f + qlx - pxc;
            float bx = 1.f - qrx + pxc;
            float ay = 1.f + qly - pyc;
            float by = 1.f - qry + pyc;
            int cx[4] = {(int)qlx - 1, (int)qrx - 1, (int)qlx - 1, (int)qrx - 1};
            int cy[4] = {(int)qly - 1, (int)qry - 1, (int)qry - 1, (int)qly - 1};
            float cw[4] = {ax * ay, bx * by, ax * by, bx * ay};
            half8 av = (half8)(_Float16)0;
#pragma unroll
            for (int k = 0; k < 4; ++k) {
                bool v = ((unsigned)cx[k] < 128u) && ((unsigned)cy[k] < 128u);
                size_t base = v ? (((size_t)((b * 128 + cx[k]) * 128 + cy[k])) << 6) : 0;
                _Float16 wk = v ? (_Float16)cw[k] : (_Float16)0.f;
                half8 u = *(const half8*)(x_t + base + cs3e);
                av += u * wk;
            }
            acc0 = __builtin_amdgcn_mfma_f32_32x32x16_f16(av, Bf0, acc0, 0, 0, 0);
            acc1 = __builtin_amdgcn_mfma_f32_32x32x16_f16(av, Bf1, acc1, 0, 0, 0);
        }
    }
    __syncthreads();  // tile dead; reuse as ep0/ep1

    // ---- epilogue: kq-pair reduce into ep0 (kq 0+1) / ep1 (kq 2+3), then summed store ----
    {
        float* epH = (float*)(S + ((kq >> 1) ? 16640 : 0));
#pragma unroll
        for (int round = 0; round < 2; ++round) {
            if ((kq & 1) == round) {
#pragma unroll
                for (int oh = 0; oh < 2; ++oh) {
                    int o = oh * 32 + (lane & 31);
                    f32x16 a = oh ? acc1 : acc0;
#pragma unroll
                    for (int reg = 0; reg < 16; ++reg) {
                        int pix = pg2 * 32 + ((reg & 3) + 8 * (reg >> 2) + 4 * (lane >> 5));
                        if (round == 0)
                            epH[o * 65 + pix] = a[reg];
                        else
                            epH[o * 65 + pix] += a[reg];
                    }
                }
            }
            __syncthreads();
        }
    }
    {
        float* e0 = (float*)S;
        float* e1 = (float*)(S + 16640);
        for (int t = tid; t < 4096; t += 512) {
            int o = t >> 6;
            int p = t & 63;
            out[(((size_t)(b * 64 + o)) << 14) + ((i + (p >> 5)) << 7) + j0 + (p & 31)] =
                e0[o * 65 + p] + e1[o * 65 + p] + conv_b[o];
        }
    }
}

extern "C" void kernel_launch(void* const* d_in, const int* in_sizes, int n_in,
                              void* d_out, int out_size, void* d_ws, size_t ws_size,
                              hipStream_t stream) {
    const float* x = (const float*)d_in[0];
    const float* p_w = (const float*)d_in[1];
    const float* p_b = (const float*)d_in[2];
    const float* conv_w = (const float*)d_in[3];
    const float* conv_b = (const float*)d_in[4];
    float* out = (float*)d_out;
    char* ws = (char*)d_ws;

    unsigned short* x_t = (unsigned short*)(ws);
    unsigned short* cwtf = (unsigned short*)(ws + CWTF_OFF);
    unsigned short* pwtf = (unsigned short*)(ws + PWTF_OFF);

    k_prep<<<728, 256, 0, stream>>>(x, (unsigned int*)x_t, conv_w, p_w, cwtf, pwtf);
    k_fused<<<1024, 512, 0, stream>>>(x_t, cwtf, pwtf, p_b, conv_b, out);
}

// Round 20
// 33.575 us; speedup vs baseline: 1.1511x; 1.1009x over previous
//
#include <hip/hip_runtime.h>
#include <math.h>

// B=4, C=64, H=W=128, OUTC=64, KS=3, taps N=9, K = 9*64 = 576. All fp16 data, f32 accum.
// ws layout (bytes):
//   x_t   fp16 [4][128][128][64]   @ 0        (8 MB) NHWC
//   cwtf  fp16 [9][4][2][64][8]    @ 8388608  (72 KB) main-conv B-frags for 32x32x16:
//         cwtf[((n*4+kq)*2+oh)*512 + lane*8 + e] = conv_w[o=oh*32+(lane&31)][c=kq*16+(lane>>5)*8+e][n]
//   pwtf  fp16 [9][2][2][64][8]    @ 8462336  (36 KB) offset-conv B-fragments (rows>=18 zero)
#define CWTF_OFF 8388608
#define PWTF_OFF (CWTF_OFF + 73728)

typedef __attribute__((ext_vector_type(8))) _Float16 half8;
typedef __attribute__((ext_vector_type(8))) unsigned short ushort8;
typedef __attribute__((ext_vector_type(4))) float f32x4;
typedef __attribute__((ext_vector_type(16))) float f32x16;
typedef __attribute__((ext_vector_type(4))) unsigned int u32x4;

__device__ inline unsigned short f2h(float f) {
    _Float16 h = (_Float16)f; return __builtin_bit_cast(unsigned short, h);
}

// ---------------- prep: x NCHW f32 -> NHWC fp16 (XCD-aligned with consumer), + weights ----------------
// k_fused consumer mapping (inverse of its chunked swizzle): XCD xcd consumes rows of batch b
// where xcd = 2*b + (i >= 64). Transpose block bid (0..511): xcd = bid&7 -> b = xcd>>1,
// i = (xcd&1)*64 + (bid>>3). Producer writes x_t into the L2 slice its consumers read.
__global__ __launch_bounds__(256) void k_prep(const float* __restrict__ x,
                                              unsigned int* __restrict__ x_t_u32,
                                              const float* __restrict__ conv_w,
                                              const float* __restrict__ p_w,
                                              unsigned short* __restrict__ cwtf,
                                              unsigned short* __restrict__ pwtf) {
    if (blockIdx.x < 512) {
        __shared__ float t[64][129];
        int xcd = blockIdx.x & 7;
        int r = blockIdx.x >> 3;
        int b = xcd >> 1;
        int i = (xcd & 1) * 64 + r;
        for (int idx = threadIdx.x; idx < 64 * 128; idx += 256) {
            int c = idx >> 7, j = idx & 127;
            t[c][j] = x[(((size_t)(b * 64 + c) * 128 + i) << 7) + j];
        }
        __syncthreads();
        unsigned int* dst = x_t_u32 + ((size_t)(b * 128 + i)) * 128 * 32;
        for (int idx2 = threadIdx.x; idx2 < 4096; idx2 += 256) {
            int j = idx2 >> 5, c2 = idx2 & 31;
            unsigned int lo = f2h(t[2 * c2][j]);
            unsigned int hi = f2h(t[2 * c2 + 1][j]);
            dst[idx2] = lo | (hi << 16);
        }
    } else {
        int tid = (blockIdx.x - 512) * 256 + threadIdx.x;
        if (tid < 36864) {
            // 32x32x16 B-frag order: e b0-2, lane b3-8, oh b9, kq b10-11, n b12+
            int e = tid & 7, lane = (tid >> 3) & 63, oh = (tid >> 9) & 1, kq = (tid >> 10) & 3, n = tid >> 12;
            int o = oh * 32 + (lane & 31);
            int c = kq * 16 + ((lane >> 5) << 3) + e;
            cwtf[tid] = f2h(conv_w[(o * 64 + c) * 9 + n]);
        } else if (tid < 36864 + 18432) {
            int t2 = tid - 36864;
            int e = t2 & 7, lane = (t2 >> 3) & 63, nb = (t2 >> 9) & 1, h = (t2 >> 10) & 1, n = t2 >> 11;
            int np = nb * 16 + (lane & 15);
            int c = h * 32 + ((lane >> 4) << 3) + e;
            pwtf[t2] = (np < 18) ? f2h(p_w[(np * 64 + c) * 9 + n]) : (unsigned short)0;
        }
    }
}

// ---------------- fused kernel (r19 verbatim: 2x32 footprint, 32x32x16 phase 3) ----------------
// Block = 64 pixels: rows (i, i+1) x cols (j0..j0+31). 8 waves (512 thr).
// Pixel p: row = p>>5, col = p&31. Tile rows i-3..i+4, cols j0-3..j0+34 (margin 3, 8 sigma).
// Phase 1/2: wave wv = (pg = wv&3 [16 px], h = wv>>2 [k-half]), 16x16x32.
// Phase 3: wave wv = (pg2 = wv&1 [32 px], kq = wv>>1 [K-quarter]), 32x32x16; one A-frag, 2 MFMAs.
// geom entry: hi16 = pre-swizzled LDS offset>>4, low16 = f16 weight; decode = (hi<<4)^csx.
#define TROWS 8
#define TCOLS 38
#define TRECS (TROWS * TCOLS)      // 304 records of 128 B (64 ch fp16)
#define TILE_B (TRECS * 128)       // 38912 B
#define OFF_OFFS TILE_B            // 4608 B  [64][18] f32 (live through phase 3 for fallback)
#define OFF_GEOM (TILE_B + 4608)   // 9216 B  [9][64][4] packed u32
#define OFF_FLAG (TILE_B + 4608 + 9216)
// Epilogue: ep0 @ 0 (kq 0+1), ep1 @ 16640 (kq 2+3), [64][65] f32 each, overlay dead tile (38912 B).

__global__ __launch_bounds__(512, 2) void k_fused(const unsigned short* __restrict__ x_t,
                                                  const unsigned short* __restrict__ cwtf,
                                                  const unsigned short* __restrict__ pwtf,
                                                  const float* __restrict__ p_b,
                                                  const float* __restrict__ conv_b,
                                                  float* __restrict__ out) {
    __shared__ __align__(16) unsigned char S[TILE_B + 4608 + 9216 + 16];
    unsigned char* tile = S;
    float* offs = (float*)(S + OFF_OFFS);
    unsigned char* geomB = S + OFF_GEOM;
    int* flagp = (int*)(S + OFF_FLAG);

    int bid0 = blockIdx.x;
    int bid = (bid0 & 7) * 128 + (bid0 >> 3);  // chunked XCD swizzle (1024 % 8 == 0)
    int b = bid >> 8;
    int rem = bid & 255;
    int i = (rem >> 2) * 2;      // i-pair base row
    int j0 = (rem & 3) * 32;     // j-quarter base col
    int ib = i - 3, jb = j0 - 3;

    int tid = threadIdx.x;
    int lane = tid & 63;
    int r15 = lane & 15;
    int g = lane >> 4;
    int wv = tid >> 6;
    int pg = wv & 3;             // phase-1 pixel group
    int h = wv >> 2;             // phase-1 k-half
    int pl = pg * 16 + r15;      // pixel index 0-63
    int cs = g + (h << 2);

    if (tid == 0) *flagp = 0;

    // ---- stage swizzled x-tile (coalesced global, swizzled ds_write) ----
    for (int u = tid; u < TRECS * 8; u += 512) {
        int rec = u >> 3, chunk = u & 7;
        int trow = rec / TCOLS;
        int tcol = rec - trow * TCOLS;
        int gr = ib + trow, gc = jb + tcol;
        bool v = ((unsigned)gr < 128u) && ((unsigned)gc < 128u);
        int grc = v ? gr : 0, gcc = v ? gc : 0;
        ushort8 val = *(const ushort8*)(x_t + (((size_t)((b * 128 + grc) * 128 + gcc)) << 6) + (chunk << 3));
        if (!v) val = (ushort8)(unsigned short)0;
        *(ushort8*)(tile + rec * 128 + ((chunk ^ (rec & 7)) << 4)) = val;
    }
    __syncthreads();

    // ---- phase 1: offset conv — 16x16x32, wave supplies its channel-half's k-block ----
    f32x4 aco0 = (f32x4)0.f, aco1 = (f32x4)0.f;
    {
        int ir = pl >> 5, jc = pl & 31;
        for (int n = 0; n < 9; ++n) {
            int du = n / 3 - 1, dv = n % 3 - 1;
            int trec = (ir + du + 3) * TCOLS + (jc + dv + 3);
            int xb = trec & 7;
            half8 a = *(const half8*)(tile + trec * 128 + ((cs ^ xb) << 4));
            const unsigned short* pb = pwtf + (((n * 2 + h) * 2) << 9) + (lane << 3);
            half8 b0 = *(const half8*)pb;
            half8 b1 = *(const half8*)(pb + 512);
            aco0 = __builtin_amdgcn_mfma_f32_16x16x32_f16(a, b0, aco0, 0, 0, 0);
            aco1 = __builtin_amdgcn_mfma_f32_16x16x32_f16(a, b1, aco1, 0, 0, 0);
        }
    }
#pragma unroll
    for (int hh = 0; hh < 2; ++hh) {
        if (h == hh) {
#pragma unroll
            for (int nb = 0; nb < 2; ++nb) {
                int np = nb * 16 + r15;
                if (np < 18) {
                    f32x4 a = nb ? aco1 : aco0;
#pragma unroll
                    for (int rr = 0; rr < 4; ++rr) {
                        int pix = pg * 16 + g * 4 + rr;
                        if (hh == 0)
                            offs[pix * 18 + np] = a[rr] + p_b[np];
                        else
                            offs[pix * 18 + np] += a[rr];
                    }
                }
            }
        }
        __syncthreads();
    }

    // ---- phase 2: bilinear geometry -> baked pre-swizzled LDS offsets ----
    for (int t = tid; t < 576; t += 512) {
        int p = t / 9;
        int n = t - p * 9;
        float ox = offs[p * 18 + n];
        float oy = offs[p * 18 + 9 + n];
        float px = ox + (float)(i + (p >> 5) + 1) + (float)(n / 3 - 1);
        float py = oy + (float)(j0 + (p & 31) + 1) + (float)(n % 3 - 1);
        float fx = floorf(px), fy = floorf(py);
        float qlx = fminf(fmaxf(fx, 0.f), 129.f);
        float qrx = fminf(fmaxf(fx + 1.f, 0.f), 129.f);
        float qly = fminf(fmaxf(fy, 0.f), 129.f);
        float qry = fminf(fmaxf(fy + 1.f, 0.f), 129.f);
        float pxc = fminf(fmaxf(px, 0.f), 129.f);
        float pyc = fminf(fmaxf(py, 0.f), 129.f);
        float ax = 1.f + qlx - pxc;
        float bx = 1.f - qrx + pxc;
        float ay = 1.f + qly - pyc;
        float by = 1.f - qry + pyc;
        int rlx = (int)qlx - 1, rrx = (int)qrx - 1;
        int rly = (int)qly - 1, rry = (int)qry - 1;
        bool bad = false;
        unsigned int pk[4];
        int cx[4] = {rlx, rrx, rlx, rrx};
        int cy[4] = {rly, rry, rry, rly};
        float cw[4] = {ax * ay, bx * by, ax * by, bx * ay};
#pragma unroll
        for (int k = 0; k < 4; ++k) {
            bool v = ((unsigned)cx[k] < 128u) && ((unsigned)cy[k] < 128u);
            bool intile = (((unsigned)(cx[k] - ib) < (unsigned)TROWS) &&
                           ((unsigned)(cy[k] - jb) < (unsigned)TCOLS));
            unsigned rec = (unsigned)(cx[k] - ib) * TCOLS + (unsigned)(cy[k] - jb);
            pk[k] = (v && intile) ? (((rec * 8u + (rec & 7u)) << 16) | f2h(cw[k])) : 0u;
            bad = bad || (v && !intile);
        }
        *(u32x4*)(geomB + ((n * 64 + p) << 4)) = (u32x4){pk[0], pk[1], pk[2], pk[3]};
        if (bad) *flagp = 1;
    }
    __syncthreads();

    // ---- phase 3: main conv — 32x32x16, wave = (pg2, kq); one A-frag feeds 2 MFMAs ----
    int pg2 = wv & 1;
    int kq = wv >> 1;
    int pl3 = pg2 * 32 + (lane & 31);                    // A-row pixel (0-63)
    unsigned csx3 = (unsigned)((kq * 2 + (lane >> 5)) << 4);  // channel chunk byte offset
    f32x16 acc0 = (f32x16)0.f, acc1 = (f32x16)0.f;
    bool fast = (*flagp == 0);

    if (fast) {
        for (int n = 0; n < 9; ++n) {
            u32x4 gq = *(const u32x4*)(geomB + ((n * 64 + pl3) << 4));
            const unsigned short* cb = cwtf + (((n * 4 + kq) * 2) << 9) + (lane << 3);
            half8 Bf0 = *(const half8*)cb;
            half8 Bf1 = *(const half8*)(cb + 512);
            half8 av = (half8)(_Float16)0;
#pragma unroll
            for (int k = 0; k < 4; ++k) {
                unsigned int p = gq[k];
                _Float16 wk = __builtin_bit_cast(_Float16, (unsigned short)(p & 0xFFFFu));
                half8 u = *(const half8*)(tile + (((p >> 16) << 4) ^ csx3));
                av += u * wk;   // v_pk_fma_f16
            }
            acc0 = __builtin_amdgcn_mfma_f32_32x32x16_f16(av, Bf0, acc0, 0, 0, 0);
            acc1 = __builtin_amdgcn_mfma_f32_32x32x16_f16(av, Bf1, acc1, 0, 0, 0);
        }
    } else {
        // rare path: recompute geometry from offs (still live), gather from global
        int cs3e = (kq * 2 + (lane >> 5)) << 3;   // channel element offset
        for (int n = 0; n < 9; ++n) {
            const unsigned short* cb = cwtf + (((n * 4 + kq) * 2) << 9) + (lane << 3);
            half8 Bf0 = *(const half8*)cb;
            half8 Bf1 = *(const half8*)(cb + 512);
            float ox = offs[pl3 * 18 + n];
            float oy = offs[pl3 * 18 + 9 + n];
            float px = ox + (float)(i + (pl3 >> 5) + 1) + (float)(n / 3 - 1);
            float py = oy + (float)(j0 + (pl3 & 31) + 1) + (float)(n % 3 - 1);
            float fx = floorf(px), fy = floorf(py);
            float qlx = fminf(fmaxf(fx, 0.f), 129.f);
            float qrx = fminf(fmaxf(fx + 1.f, 0.f), 129.f);
            float qly = fminf(fmaxf(fy, 0.f), 129.f);
            float qry = fminf(fmaxf(fy + 1.f, 0.f), 129.f);
            float pxc = fminf(fmaxf(px, 0.f), 129.f);
            float pyc = fminf(fmaxf(py, 0.f), 129.f);
            float ax = 1.f + qlx - pxc;
            float bx = 1.f - qrx + pxc;
            float ay = 1.f + qly - pyc;
            float by = 1.f - qry + pyc;
            int cx[4] = {(int)qlx - 1, (int)qrx - 1, (int)qlx - 1, (int)qrx - 1};
            int cy[4] = {(int)qly - 1, (int)qry - 1, (int)qry - 1, (int)qly - 1};
            float cw[4] = {ax * ay, bx * by, ax * by, bx * ay};
            half8 av = (half8)(_Float16)0;
#pragma unroll
            for (int k = 0; k < 4; ++k) {
                bool v = ((unsigned)cx[k] < 128u) && ((unsigned)cy[k] < 128u);
                size_t base = v ? (((size_t)((b * 128 + cx[k]) * 128 + cy[k])) << 6) : 0;
                _Float16 wk = v ? (_Float16)cw[k] : (_Float16)0.f;
                half8 u = *(const half8*)(x_t + base + cs3e);
                av += u * wk;
            }
            acc0 = __builtin_amdgcn_mfma_f32_32x32x16_f16(av, Bf0, acc0, 0, 0, 0);
            acc1 = __builtin_amdgcn_mfma_f32_32x32x16_f16(av, Bf1, acc1, 0, 0, 0);
        }
    }
    __syncthreads();  // tile dead; reuse as ep0/ep1

    // ---- epilogue: kq-pair reduce into ep0 (kq 0+1) / ep1 (kq 2+3), then summed store ----
    {
        float* epH = (float*)(S + ((kq >> 1) ? 16640 : 0));
#pragma unroll
        for (int round = 0; round < 2; ++round) {
            if ((kq & 1) == round) {
#pragma unroll
                for (int oh = 0; oh < 2; ++oh) {
                    int o = oh * 32 + (lane & 31);
                    f32x16 a = oh ? acc1 : acc0;
#pragma unroll
                    for (int reg = 0; reg < 16; ++reg) {
                        int pix = pg2 * 32 + ((reg & 3) + 8 * (reg >> 2) + 4 * (lane >> 5));
                        if (round == 0)
                            epH[o * 65 + pix] = a[reg];
                        else
                            epH[o * 65 + pix] += a[reg];
                    }
                }
            }
            __syncthreads();
        }
    }
    {
        float* e0 = (float*)S;
        float* e1 = (float*)(S + 16640);
        for (int t = tid; t < 4096; t += 512) {
            int o = t >> 6;
            int p = t & 63;
            out[(((size_t)(b * 64 + o)) << 14) + ((i + (p >> 5)) << 7) + j0 + (p & 31)] =
                e0[o * 65 + p] + e1[o * 65 + p] + conv_b[o];
        }
    }
}

extern "C" void kernel_launch(void* const* d_in, const int* in_sizes, int n_in,
                              void* d_out, int out_size, void* d_ws, size_t ws_size,
                              hipStream_t stream) {
    const float* x = (const float*)d_in[0];
    const float* p_w = (const float*)d_in[1];
    const float* p_b = (const float*)d_in[2];
    const float* conv_w = (const float*)d_in[3];
    const float* conv_b = (const float*)d_in[4];
    float* out = (float*)d_out;
    char* ws = (char*)d_ws;

    unsigned short* x_t = (unsigned short*)(ws);
    unsigned short* cwtf = (unsigned short*)(ws + CWTF_OFF);
    unsigned short* pwtf = (unsigned short*)(ws + PWTF_OFF);

    k_prep<<<728, 256, 0, stream>>>(x, (unsigned int*)x_t, conv_w, p_w, cwtf, pwtf);
    k_fused<<<1024, 512, 0, stream>>>(x_t, cwtf, pwtf, p_b, conv_b, out);
}

// Round 21
// 31.801 us; speedup vs baseline: 1.2153x; 1.0558x over previous
//
#include <hip/hip_runtime.h>
#include <math.h>

// B=4, C=64, H=W=128, OUTC=64, KS=3, taps N=9, K = 9*64 = 576. All fp16 data, f32 accum.
// ws layout (bytes):
//   x_t   fp16 [4][128][128][64]   @ 0        (8 MB) NHWC
//   cwtf  fp16 [9][4][2][64][8]    @ 8388608  (72 KB) main-conv B-frags for 32x32x16:
//         cwtf[((n*4+kq)*2+oh)*512 + lane*8 + e] = conv_w[o=oh*32+(lane&31)][c=kq*16+(lane>>5)*8+e][n]
//   pwtf  fp16 [9][2][2][64][8]    @ 8462336  (36 KB) offset-conv B-fragments (rows>=18 zero)
#define CWTF_OFF 8388608
#define PWTF_OFF (CWTF_OFF + 73728)

typedef __attribute__((ext_vector_type(8))) _Float16 half8;
typedef __attribute__((ext_vector_type(8))) unsigned short ushort8;
typedef __attribute__((ext_vector_type(4))) float f32x4;
typedef __attribute__((ext_vector_type(16))) float f32x16;
typedef __attribute__((ext_vector_type(4))) unsigned int u32x4;

__device__ inline unsigned short f2h(float f) {
    _Float16 h = (_Float16)f; return __builtin_bit_cast(unsigned short, h);
}

// ---------------- prep: x NCHW f32 -> NHWC fp16 (XCD-aligned with consumer), + weights ----------------
// k_fused consumer mapping (inverse of its chunked swizzle): XCD xcd consumes rows of batch b
// where xcd = 2*b + (i >= 64). Transpose block bid (0..511): xcd = bid&7 -> b = xcd>>1,
// i = (xcd&1)*64 + (bid>>3). Producer writes x_t into the L2 slice its consumers read.
__global__ __launch_bounds__(256) void k_prep(const float* __restrict__ x,
                                              unsigned int* __restrict__ x_t_u32,
                                              const float* __restrict__ conv_w,
                                              const float* __restrict__ p_w,
                                              unsigned short* __restrict__ cwtf,
                                              unsigned short* __restrict__ pwtf) {
    if (blockIdx.x < 512) {
        __shared__ float t[64][129];
        int xcd = blockIdx.x & 7;
        int r = blockIdx.x >> 3;
        int b = xcd >> 1;
        int i = (xcd & 1) * 64 + r;
        for (int idx = threadIdx.x; idx < 64 * 128; idx += 256) {
            int c = idx >> 7, j = idx & 127;
            t[c][j] = x[(((size_t)(b * 64 + c) * 128 + i) << 7) + j];
        }
        __syncthreads();
        unsigned int* dst = x_t_u32 + ((size_t)(b * 128 + i)) * 128 * 32;
        for (int idx2 = threadIdx.x; idx2 < 4096; idx2 += 256) {
            int j = idx2 >> 5, c2 = idx2 & 31;
            unsigned int lo = f2h(t[2 * c2][j]);
            unsigned int hi = f2h(t[2 * c2 + 1][j]);
            dst[idx2] = lo | (hi << 16);
        }
    } else {
        int tid = (blockIdx.x - 512) * 256 + threadIdx.x;
        if (tid < 36864) {
            // 32x32x16 B-frag order: e b0-2, lane b3-8, oh b9, kq b10-11, n b12+
            int e = tid & 7, lane = (tid >> 3) & 63, oh = (tid >> 9) & 1, kq = (tid >> 10) & 3, n = tid >> 12;
            int o = oh * 32 + (lane & 31);
            int c = kq * 16 + ((lane >> 5) << 3) + e;
            cwtf[tid] = f2h(conv_w[(o * 64 + c) * 9 + n]);
        } else if (tid < 36864 + 18432) {
            int t2 = tid - 36864;
            int e = t2 & 7, lane = (t2 >> 3) & 63, nb = (t2 >> 9) & 1, h = (t2 >> 10) & 1, n = t2 >> 11;
            int np = nb * 16 + (lane & 15);
            int c = h * 32 + ((lane >> 4) << 3) + e;
            pwtf[t2] = (np < 18) ? f2h(p_w[(np * 64 + c) * 9 + n]) : (unsigned short)0;
        }
    }
}

// ---------------- fused kernel (r20 verbatim except __launch_bounds__(512, 6) -> 3 blocks/CU) ----------------
// Block = 64 pixels: rows (i, i+1) x cols (j0..j0+31). 8 waves (512 thr).
// Pixel p: row = p>>5, col = p&31. Tile rows i-3..i+4, cols j0-3..j0+34 (margin 3, 8 sigma).
// Phase 1/2: wave wv = (pg = wv&3 [16 px], h = wv>>2 [k-half]), 16x16x32.
// Phase 3: wave wv = (pg2 = wv&1 [32 px], kq = wv>>1 [K-quarter]), 32x32x16; one A-frag, 2 MFMAs.
// geom entry: hi16 = pre-swizzled LDS offset>>4, low16 = f16 weight; decode = (hi<<4)^csx.
// LDS total 52.75 KB -> 3 blocks/CU when VGPR <= 85 (lb 512,6).
#define TROWS 8
#define TCOLS 38
#define TRECS (TROWS * TCOLS)      // 304 records of 128 B (64 ch fp16)
#define TILE_B (TRECS * 128)       // 38912 B
#define OFF_OFFS TILE_B            // 4608 B  [64][18] f32 (live through phase 3 for fallback)
#define OFF_GEOM (TILE_B + 4608)   // 9216 B  [9][64][4] packed u32
#define OFF_FLAG (TILE_B + 4608 + 9216)
// Epilogue: ep0 @ 0 (kq 0+1), ep1 @ 16640 (kq 2+3), [64][65] f32 each, overlay dead tile (38912 B).

__global__ __launch_bounds__(512, 6) void k_fused(const unsigned short* __restrict__ x_t,
                                                  const unsigned short* __restrict__ cwtf,
                                                  const unsigned short* __restrict__ pwtf,
                                                  const float* __restrict__ p_b,
                                                  const float* __restrict__ conv_b,
                                                  float* __restrict__ out) {
    __shared__ __align__(16) unsigned char S[TILE_B + 4608 + 9216 + 16];
    unsigned char* tile = S;
    float* offs = (float*)(S + OFF_OFFS);
    unsigned char* geomB = S + OFF_GEOM;
    int* flagp = (int*)(S + OFF_FLAG);

    int bid0 = blockIdx.x;
    int bid = (bid0 & 7) * 128 + (bid0 >> 3);  // chunked XCD swizzle (1024 % 8 == 0)
    int b = bid >> 8;
    int rem = bid & 255;
    int i = (rem >> 2) * 2;      // i-pair base row
    int j0 = (rem & 3) * 32;     // j-quarter base col
    int ib = i - 3, jb = j0 - 3;

    int tid = threadIdx.x;
    int lane = tid & 63;
    int r15 = lane & 15;
    int g = lane >> 4;
    int wv = tid >> 6;
    int pg = wv & 3;             // phase-1 pixel group
    int h = wv >> 2;             // phase-1 k-half
    int pl = pg * 16 + r15;      // pixel index 0-63
    int cs = g + (h << 2);

    if (tid == 0) *flagp = 0;

    // ---- stage swizzled x-tile (coalesced global, swizzled ds_write) ----
    for (int u = tid; u < TRECS * 8; u += 512) {
        int rec = u >> 3, chunk = u & 7;
        int trow = rec / TCOLS;
        int tcol = rec - trow * TCOLS;
        int gr = ib + trow, gc = jb + tcol;
        bool v = ((unsigned)gr < 128u) && ((unsigned)gc < 128u);
        int grc = v ? gr : 0, gcc = v ? gc : 0;
        ushort8 val = *(const ushort8*)(x_t + (((size_t)((b * 128 + grc) * 128 + gcc)) << 6) + (chunk << 3));
        if (!v) val = (ushort8)(unsigned short)0;
        *(ushort8*)(tile + rec * 128 + ((chunk ^ (rec & 7)) << 4)) = val;
    }
    __syncthreads();

    // ---- phase 1: offset conv — 16x16x32, wave supplies its channel-half's k-block ----
    f32x4 aco0 = (f32x4)0.f, aco1 = (f32x4)0.f;
    {
        int ir = pl >> 5, jc = pl & 31;
        for (int n = 0; n < 9; ++n) {
            int du = n / 3 - 1, dv = n % 3 - 1;
            int trec = (ir + du + 3) * TCOLS + (jc + dv + 3);
            int xb = trec & 7;
            half8 a = *(const half8*)(tile + trec * 128 + ((cs ^ xb) << 4));
            const unsigned short* pb = pwtf + (((n * 2 + h) * 2) << 9) + (lane << 3);
            half8 b0 = *(const half8*)pb;
            half8 b1 = *(const half8*)(pb + 512);
            aco0 = __builtin_amdgcn_mfma_f32_16x16x32_f16(a, b0, aco0, 0, 0, 0);
            aco1 = __builtin_amdgcn_mfma_f32_16x16x32_f16(a, b1, aco1, 0, 0, 0);
        }
    }
#pragma unroll
    for (int hh = 0; hh < 2; ++hh) {
        if (h == hh) {
#pragma unroll
            for (int nb = 0; nb < 2; ++nb) {
                int np = nb * 16 + r15;
                if (np < 18) {
                    f32x4 a = nb ? aco1 : aco0;
#pragma unroll
                    for (int rr = 0; rr < 4; ++rr) {
                        int pix = pg * 16 + g * 4 + rr;
                        if (hh == 0)
                            offs[pix * 18 + np] = a[rr] + p_b[np];
                        else
                            offs[pix * 18 + np] += a[rr];
                    }
                }
            }
        }
        __syncthreads();
    }

    // ---- phase 2: bilinear geometry -> baked pre-swizzled LDS offsets ----
    for (int t = tid; t < 576; t += 512) {
        int p = t / 9;
        int n = t - p * 9;
        float ox = offs[p * 18 + n];
        float oy = offs[p * 18 + 9 + n];
        float px = ox + (float)(i + (p >> 5) + 1) + (float)(n / 3 - 1);
        float py = oy + (float)(j0 + (p & 31) + 1) + (float)(n % 3 - 1);
        float fx = floorf(px), fy = floorf(py);
        float qlx = fminf(fmaxf(fx, 0.f), 129.f);
        float qrx = fminf(fmaxf(fx + 1.f, 0.f), 129.f);
        float qly = fminf(fmaxf(fy, 0.f), 129.f);
        float qry = fminf(fmaxf(fy + 1.f, 0.f), 129.f);
        float pxc = fminf(fmaxf(px, 0.f), 129.f);
        float pyc = fminf(fmaxf(py, 0.f), 129.f);
        float ax = 1.f + qlx - pxc;
        float bx = 1.f - qrx + pxc;
        float ay = 1.f + qly - pyc;
        float by = 1.f - qry + pyc;
        int rlx = (int)qlx - 1, rrx = (int)qrx - 1;
        int rly = (int)qly - 1, rry = (int)qry - 1;
        bool bad = false;
        unsigned int pk[4];
        int cx[4] = {rlx, rrx, rlx, rrx};
        int cy[4] = {rly, rry, rry, rly};
        float cw[4] = {ax * ay, bx * by, ax * by, bx * ay};
#pragma unroll
        for (int k = 0; k < 4; ++k) {
            bool v = ((unsigned)cx[k] < 128u) && ((unsigned)cy[k] < 128u);
            bool intile = (((unsigned)(cx[k] - ib) < (unsigned)TROWS) &&
                           ((unsigned)(cy[k] - jb) < (unsigned)TCOLS));
            unsigned rec = (unsigned)(cx[k] - ib) * TCOLS + (unsigned)(cy[k] - jb);
            pk[k] = (v && intile) ? (((rec * 8u + (rec & 7u)) << 16) | f2h(cw[k])) : 0u;
            bad = bad || (v && !intile);
        }
        *(u32x4*)(geomB + ((n * 64 + p) << 4)) = (u32x4){pk[0], pk[1], pk[2], pk[3]};
        if (bad) *flagp = 1;
    }
    __syncthreads();

    // ---- phase 3: main conv — 32x32x16, wave = (pg2, kq); one A-frag feeds 2 MFMAs ----
    int pg2 = wv & 1;
    int kq = wv >> 1;
    int pl3 = pg2 * 32 + (lane & 31);                    // A-row pixel (0-63)
    unsigned csx3 = (unsigned)((kq * 2 + (lane >> 5)) << 4);  // channel chunk byte offset
    f32x16 acc0 = (f32x16)0.f, acc1 = (f32x16)0.f;
    bool fast = (*flagp == 0);

    if (fast) {
        for (int n = 0; n < 9; ++n) {
            u32x4 gq = *(const u32x4*)(geomB + ((n * 64 + pl3) << 4));
            const unsigned short* cb = cwtf + (((n * 4 + kq) * 2) << 9) + (lane << 3);
            half8 Bf0 = *(const half8*)cb;
            half8 Bf1 = *(const half8*)(cb + 512);
            half8 av = (half8)(_Float16)0;
#pragma unroll
            for (int k = 0; k < 4; ++k) {
                unsigned int p = gq[k];
                _Float16 wk = __builtin_bit_cast(_Float16, (unsigned short)(p & 0xFFFFu));
                half8 u = *(const half8*)(tile + (((p >> 16) << 4) ^ csx3));
                av += u * wk;   // v_pk_fma_f16
            }
            acc0 = __builtin_amdgcn_mfma_f32_32x32x16_f16(av, Bf0, acc0, 0, 0, 0);
            acc1 = __builtin_amdgcn_mfma_f32_32x32x16_f16(av, Bf1, acc1, 0, 0, 0);
        }
    } else {
        // rare path: recompute geometry from offs (still live), gather from global
        int cs3e = (kq * 2 + (lane >> 5)) << 3;   // channel element offset
        for (int n = 0; n < 9; ++n) {
            const unsigned short* cb = cwtf + (((n * 4 + kq) * 2) << 9) + (lane << 3);
            half8 Bf0 = *(const half8*)cb;
            half8 Bf1 = *(const half8*)(cb + 512);
            float ox = offs[pl3 * 18 + n];
            float oy = offs[pl3 * 18 + 9 + n];
            float px = ox + (float)(i + (pl3 >> 5) + 1) + (float)(n / 3 - 1);
            float py = oy + (float)(j0 + (pl3 & 31) + 1) + (float)(n % 3 - 1);
            float fx = floorf(px), fy = floorf(py);
            float qlx = fminf(fmaxf(fx, 0.f), 129.f);
            float qrx = fminf(fmaxf(fx + 1.f, 0.f), 129.f);
            float qly = fminf(fmaxf(fy, 0.f), 129.f);
            float qry = fminf(fmaxf(fy + 1.f, 0.f), 129.f);
            float pxc = fminf(fmaxf(px, 0.f), 129.f);
            float pyc = fminf(fmaxf(py, 0.f), 129.f);
            float ax = 1.f + qlx - pxc;
            float bx = 1.f - qrx + pxc;
            float ay = 1.f + qly - pyc;
            float by = 1.f - qry + pyc;
            int cx[4] = {(int)qlx - 1, (int)qrx - 1, (int)qlx - 1, (int)qrx - 1};
            int cy[4] = {(int)qly - 1, (int)qry - 1, (int)qry - 1, (int)qly - 1};
            float cw[4] = {ax * ay, bx * by, ax * by, bx * ay};
            half8 av = (half8)(_Float16)0;
#pragma unroll
            for (int k = 0; k < 4; ++k) {
                bool v = ((unsigned)cx[k] < 128u) && ((unsigned)cy[k] < 128u);
                size_t base = v ? (((size_t)((b * 128 + cx[k]) * 128 + cy[k])) << 6) : 0;
                _Float16 wk = v ? (_Float16)cw[k] : (_Float16)0.f;
                half8 u = *(const half8*)(x_t + base + cs3e);
                av += u * wk;
            }
            acc0 = __builtin_amdgcn_mfma_f32_32x32x16_f16(av, Bf0, acc0, 0, 0, 0);
            acc1 = __builtin_amdgcn_mfma_f32_32x32x16_f16(av, Bf1, acc1, 0, 0, 0);
        }
    }
    __syncthreads();  // tile dead; reuse as ep0/ep1

    // ---- epilogue: kq-pair reduce into ep0 (kq 0+1) / ep1 (kq 2+3), then summed store ----
    {
        float* epH = (float*)(S + ((kq >> 1) ? 16640 : 0));
#pragma unroll
        for (int round = 0; round < 2; ++round) {
            if ((kq & 1) == round) {
#pragma unroll
                for (int oh = 0; oh < 2; ++oh) {
                    int o = oh * 32 + (lane & 31);
                    f32x16 a = oh ? acc1 : acc0;
#pragma unroll
                    for (int reg = 0; reg < 16; ++reg) {
                        int pix = pg2 * 32 + ((reg & 3) + 8 * (reg >> 2) + 4 * (lane >> 5));
                        if (round == 0)
                            epH[o * 65 + pix] = a[reg];
                        else
                            epH[o * 65 + pix] += a[reg];
                    }
                }
            }
            __syncthreads();
        }
    }
    {
        float* e0 = (float*)S;
        float* e1 = (float*)(S + 16640);
        for (int t = tid; t < 4096; t += 512) {
            int o = t >> 6;
            int p = t & 63;
            out[(((size_t)(b * 64 + o)) << 14) + ((i + (p >> 5)) << 7) + j0 + (p & 31)] =
                e0[o * 65 + p] + e1[o * 65 + p] + conv_b[o];
        }
    }
}

extern "C" void kernel_launch(void* const* d_in, const int* in_sizes, int n_in,
                              void* d_out, int out_size, void* d_ws, size_t ws_size,
                              hipStream_t stream) {
    const float* x = (const float*)d_in[0];
    const float* p_w = (const float*)d_in[1];
    const float* p_b = (const float*)d_in[2];
    const float* conv_w = (const float*)d_in[3];
    const float* conv_b = (const float*)d_in[4];
    float* out = (float*)d_out;
    char* ws = (char*)d_ws;

    unsigned short* x_t = (unsigned short*)(ws);
    unsigned short* cwtf = (unsigned short*)(ws + CWTF_OFF);
    unsigned short* pwtf = (unsigned short*)(ws + PWTF_OFF);

    k_prep<<<728, 256, 0, stream>>>(x, (unsigned int*)x_t, conv_w, p_w, cwtf, pwtf);
    k_fused<<<1024, 512, 0, stream>>>(x_t, cwtf, pwtf, p_b, conv_b, out);
}